// Round 1
// 94.162 us; speedup vs baseline: 1.0236x; 1.0236x over previous
//
#include <hip/hip_runtime.h>
#include <hip/hip_fp16.h>
#include <math.h>

// Problem constants: B=8, T=64, R=100, TH=768, IH=1024, P=N=512
#define B_  8
#define T_  64
#define R_  100
#define TH_ 768
#define IH_ 1024
#define P_  512
#define N_  512

#define CTANH 2.88539008177792681f   // 2*log2(e): tanh(x) = 1 - 2/(1+exp2(CTANH*x))

typedef short short8  __attribute__((ext_vector_type(8)));
typedef float floatx4 __attribute__((ext_vector_type(4)));

__device__ __forceinline__ ushort f2bf(float f) {
  union { float f; unsigned int u; } v; v.f = f;
  unsigned int r = v.u + 0x7FFFu + ((v.u >> 16) & 1u);   // RNE
  return (ushort)(r >> 16);
}

// ---------------------------------------------------------------------------
// MFMA bf16 GEMM + bias + exact GELU -> stores Eq = exp2(CTANH*gelu) in f16.
// R5 change: epilogue stores the EXPONENTIAL of the (CTANH-scaled) activation
// instead of the activation itself. tanh(q+k) = 1 - 2/(Eq*Ek+1), so the fuse
// kernel's 26.2M exp2s collapse into 671K here (2 per output element).
// GELU min is -0.17 => Eq >= 0.71 (no underflow/NaN path); overflow to f16
// inf yields rcp->0 => tanh==1, the correct saturation.
// Also computes swb = sum(w) + b once (block 0, wave 0) into ws scalar.
// In-block split-K=4: 1024 threads = 4 splits x 4 waves. Tile 64m x 32n.
// ---------------------------------------------------------------------------
#define PADK 40

__global__ __launch_bounds__(1024) void mfma_linear_gelu_exp_sk4(
    const float* __restrict__ encT, const float* __restrict__ Wq,
    const float* __restrict__ bq, __half* __restrict__ qout,
    const float* __restrict__ encI, const float* __restrict__ Wk,
    const float* __restrict__ bk, __half* __restrict__ kout,
    const float* __restrict__ wvec, const float* __restrict__ bscalar,
    float* __restrict__ swb) {
  const int rt = blockIdx.y;
  const bool isQ = rt < 8;
  const float* __restrict__ X = isQ ? encT : encI;
  const float* __restrict__ W = isQ ? Wq : Wk;
  const float* __restrict__ bias = isQ ? bq : bk;
  __half* __restrict__ Y = isQ ? qout : kout;
  const int M    = isQ ? (B_ * T_) : (B_ * R_);
  const int KDIM = isQ ? TH_ : IH_;
  const int row0 = (isQ ? rt : (rt - 8)) * 64;
  const int col0 = blockIdx.x * 32;
  const int kq   = KDIM >> 2;              // k-quarter: 192 or 256
  const int ntiles = kq / 32;              // 6 (Q) or 8 (K)

  __shared__ ushort As[4][64 * PADK];      // per-split A: As[sp][m*PADK+k]
  __shared__ ushort Bs[4][32 * PADK];      // per-split B^T: Bs[sp][n*PADK+k]
  __shared__ float  red[2][64 * 33];       // reduce buffers (row-padded)

  const int tid = threadIdx.x;
  const int sp  = tid >> 8;                // split 0..3
  const int t   = tid & 255;
  const int kbase = sp * kq;

  // A loader (per split): row t>>2, k-chunk (t&3)*8
  const int arow = t >> 2;
  const int akq  = (t & 3) * 8;
  const int arowc = min(row0 + arow, M - 1);
  const float* __restrict__ Xp = X + (size_t)arowc * KDIM + kbase + akq;

  // B loader (per split): k-pair (t>>4)*2, col-pair (t&15)*2
  const int bkp = (t >> 4) * 2;
  const int bn2 = (t & 15) * 2;
  const float* __restrict__ Wp = W + (size_t)(kbase + bkp) * N_ + col0 + bn2;

  // compute mapping: wave within split covers 16 rows x 32 cols
  const int wv = t >> 6;                   // 0..3
  const int lane = t & 63;
  const int wm = wv * 16;
  const int l15 = lane & 15;
  const int q8  = (lane >> 4) * 8;
  const int q4  = (lane >> 4) * 4;

  floatx4 acc0 = {0.f,0.f,0.f,0.f}, acc1 = {0.f,0.f,0.f,0.f};

  float4 a0 = *(const float4*)(Xp);
  float4 a1 = *(const float4*)(Xp + 4);
  float2 b0 = *(const float2*)(Wp);
  float2 b1 = *(const float2*)(Wp + N_);

  for (int kt = 0; kt < ntiles; ++kt) {
    {
      short8 pk;
      pk[0] = (short)f2bf(a0.x); pk[1] = (short)f2bf(a0.y);
      pk[2] = (short)f2bf(a0.z); pk[3] = (short)f2bf(a0.w);
      pk[4] = (short)f2bf(a1.x); pk[5] = (short)f2bf(a1.y);
      pk[6] = (short)f2bf(a1.z); pk[7] = (short)f2bf(a1.w);
      *(short8*)&As[sp][arow * PADK + akq] = pk;
    }
    {
      unsigned int p0 = (unsigned int)f2bf(b0.x) | ((unsigned int)f2bf(b1.x) << 16);
      unsigned int p1 = (unsigned int)f2bf(b0.y) | ((unsigned int)f2bf(b1.y) << 16);
      *(unsigned int*)&Bs[sp][(bn2 + 0) * PADK + bkp] = p0;
      *(unsigned int*)&Bs[sp][(bn2 + 1) * PADK + bkp] = p1;
    }
    __syncthreads();

    if (kt + 1 < ntiles) {
      const int kb = (kt + 1) * 32;
      a0 = *(const float4*)(Xp + kb);
      a1 = *(const float4*)(Xp + kb + 4);
      b0 = *(const float2*)(Wp + (size_t)kb * N_);
      b1 = *(const float2*)(Wp + (size_t)(kb + 1) * N_);
    }

    short8 af  = *(const short8*)&As[sp][(wm + l15) * PADK + q8];
    short8 bf0 = *(const short8*)&Bs[sp][(l15) * PADK + q8];
    short8 bf1 = *(const short8*)&Bs[sp][(16 + l15) * PADK + q8];
    acc0 = __builtin_amdgcn_mfma_f32_16x16x32_bf16(af, bf0, acc0, 0, 0, 0);
    acc1 = __builtin_amdgcn_mfma_f32_16x16x32_bf16(af, bf1, acc1, 0, 0, 0);
    __syncthreads();
  }

  // cross-split reduce: splits 2,3 -> layers 0,1; add into 0,1; split1 -> layer0
  if (sp >= 2) {
    float* L = red[sp - 2];
    #pragma unroll
    for (int j = 0; j < 4; ++j) {
      L[(wm + q4 + j) * 33 + l15]      = acc0[j];
      L[(wm + q4 + j) * 33 + 16 + l15] = acc1[j];
    }
  }
  __syncthreads();
  if (sp < 2) {
    const float* L = red[sp];
    #pragma unroll
    for (int j = 0; j < 4; ++j) {
      acc0[j] += L[(wm + q4 + j) * 33 + l15];
      acc1[j] += L[(wm + q4 + j) * 33 + 16 + l15];
    }
  }
  __syncthreads();
  if (sp == 1) {
    float* L = red[0];
    #pragma unroll
    for (int j = 0; j < 4; ++j) {
      L[(wm + q4 + j) * 33 + l15]      = acc0[j];
      L[(wm + q4 + j) * 33 + 16 + l15] = acc1[j];
    }
  }
  __syncthreads();
  if (sp == 0) {
    const float* L = red[0];
    const float is2 = 0.70710678118654752f;
    const float bia0 = bias[col0 + l15];
    const float bia1 = bias[col0 + 16 + l15];
    #pragma unroll
    for (int j = 0; j < 4; ++j) {
      const int row = row0 + wm + q4 + j;
      if (row < M) {
        float v0 = acc0[j] + L[(wm + q4 + j) * 33 + l15] + bia0;
        float v1 = acc1[j] + L[(wm + q4 + j) * 33 + 16 + l15] + bia1;
        v0 = 0.5f * v0 * (1.f + erff(v0 * is2));       // exact GELU
        v1 = 0.5f * v1 * (1.f + erff(v1 * is2));
        // store exponential form: Eq/Ek = exp2(CTANH * gelu)
        Y[(size_t)row * N_ + col0 + l15]      = __float2half(__builtin_amdgcn_exp2f(CTANH * v0));
        Y[(size_t)row * N_ + col0 + 16 + l15] = __float2half(__builtin_amdgcn_exp2f(CTANH * v1));
      }
    }
  }

  // one wave computes swb = sum(w) + b (reused by every fuse output)
  if (blockIdx.x == 0 && blockIdx.y == 0 && tid < 64) {
    float s = 0.f;
    const float* wp = wvec + tid * 8;
    #pragma unroll
    for (int j = 0; j < 8; ++j) s += wp[j];
    #pragma unroll
    for (int off = 1; off < 64; off <<= 1) s += __shfl_xor(s, off, 64);
    if (tid == 0) swb[0] = s + bscalar[0];
  }
}

// ---------------------------------------------------------------------------
// Fusion on f16 exponentials: out[b,t,r] = swb - 2*sum_p w_p/(Eq_p*Ek_p+1) + mask.
// R5: exp2 factored out of the inner loop (precomputed in GEMM epilogue).
// Inner loop per half2: pk_mul, 2 cvt, 2 add, 2 rcp, 2 fma = 9 instrs
// (2 transcendental) vs prior 13 (4 transcendental): issue cost 800->480
// cyc/wave. One wave = one rg (4 r's, 16 lanes each, 32 p/lane). Grid (512,7).
// ---------------------------------------------------------------------------
__global__ __launch_bounds__(256) void fuse_kernel_exp(
    const __half* __restrict__ q, const __half* __restrict__ k,
    const float* __restrict__ w, const float* __restrict__ swb,
    const float* __restrict__ mask, float* __restrict__ out) {
  const int bt = blockIdx.x;               // 0..511
  const int wave = threadIdx.x >> 6;
  const int rg = blockIdx.y * 4 + wave;    // 0..27
  if (rg >= 25) return;                    // whole-wave exit; no barriers used
  const int lane = threadIdx.x & 63;
  const int sub  = lane >> 4;              // r within group of 4
  const int pi   = lane & 15;              // p-slice
  const int r = rg * 4 + sub;              // 0..99
  const int b = bt >> 6;

  const __half* __restrict__ qp = q + (size_t)bt * P_ + pi * 8;
  const __half* __restrict__ kp = k + (size_t)(b * R_ + r) * P_ + pi * 8;
  const float* __restrict__ wp = w + pi * 8;

  float acc0 = 0.f, acc1 = 0.f;
  #pragma unroll
  for (int i = 0; i < 4; ++i) {
    union { float4 f; __half2 h[4]; } qu, ku;
    qu.f = *(const float4*)(qp + i * 128);
    ku.f = *(const float4*)(kp + i * 128);
    float4 w0 = *(const float4*)(wp + i * 128);
    float4 w1 = *(const float4*)(wp + i * 128 + 4);
    #pragma unroll
    for (int e = 0; e < 4; ++e) {
      __half2 m = __hmul2(qu.h[e], ku.h[e]);          // Eq*Ek (inf-safe)
      float x0 = __low2float(m);
      float x1 = __high2float(m);
      float d0 = __builtin_amdgcn_rcpf(x0 + 1.f);     // 1/(E+1); rcp(inf)=0
      float d1 = __builtin_amdgcn_rcpf(x1 + 1.f);
      const float we0 = (e == 0) ? w0.x : (e == 1) ? w0.z : (e == 2) ? w1.x : w1.z;
      const float we1 = (e == 0) ? w0.y : (e == 1) ? w0.w : (e == 2) ? w1.y : w1.w;
      acc0 = fmaf(we0, d0, acc0);
      acc1 = fmaf(we1, d1, acc1);
    }
  }
  float acc = acc0 + acc1;
  #pragma unroll
  for (int off = 1; off < 16; off <<= 1) acc += __shfl_xor(acc, off, 64);

  if (pi == 0) {
    // sum_p w*tanh = sum(w) - 2*acc; swb already holds sum(w)+b
    out[(size_t)bt * R_ + r] = fmaf(-2.f, acc, swb[0]) + mask[(size_t)bt * R_ + r];
  }
}

// ---------------------------------------------------------------------------
extern "C" void kernel_launch(void* const* d_in, const int* in_sizes, int n_in,
                              void* d_out, int out_size, void* d_ws, size_t ws_size,
                              hipStream_t stream) {
  const float* encT = (const float*)d_in[0];
  const float* encI = (const float*)d_in[1];
  const float* mask = (const float*)d_in[2];
  const float* Wq   = (const float*)d_in[3];
  const float* bq   = (const float*)d_in[4];
  const float* Wk   = (const float*)d_in[5];
  const float* bk   = (const float*)d_in[6];
  const float* w    = (const float*)d_in[7];
  const float* bsc  = (const float*)d_in[8];
  float* out = (float*)d_out;

  __half* q = (__half*)d_ws;               // [512, 512] f16: exp2(CTANH*gelu)
  __half* k = q + (size_t)B_ * T_ * P_;    // [800, 512] f16: exp2(CTANH*gelu)
  float* swb = (float*)(k + (size_t)B_ * R_ * P_);  // scalar: sum(w)+b

  dim3 grid(N_ / 32, 8 + 13);              // 336 blocks x 1024 threads
  mfma_linear_gelu_exp_sk4<<<grid, 1024, 0, stream>>>(encT, Wq, bq, q,
                                                      encI, Wk, bk, k,
                                                      w, bsc, swb);

  fuse_kernel_exp<<<dim3(512, 7), 256, 0, stream>>>(q, k, w, swb, mask, out);
}